// Round 12
// baseline (461.353 us; speedup 1.0000x reference)
//
#include <hip/hip_runtime.h>

#define NB 8
#define NV 100000
#define NE 300000
#define CLIPV 0.9999999f  // 1 - 1e-7 rounded to f32

#define TPB 256
#define PPB (TPB / 2)                   // 128 lane-pairs per block
#define EPT 2                           // edges per pair
#define EPB2 (PPB * EPT)                // 256 edges per block
#define CHUNKS2 ((NE + EPB2 - 1) / EPB2)
#define VCHUNKS ((NV + TPB - 1) / TPB)

#define PK_OFF 256                      // byte offset of packed verts in ws
#define PK_BYTES ((size_t)NB * NV * 8 * sizeof(float))

typedef int v4i __attribute__((ext_vector_type(4)));
typedef float v4f __attribute__((ext_vector_type(4)));

struct F3 { float x, y, z; };

__device__ __forceinline__ F3 sub3(F3 a, F3 b) {
    F3 r; r.x = a.x - b.x; r.y = a.y - b.y; r.z = a.z - b.z; return r;
}
__device__ __forceinline__ F3 cross3(F3 a, F3 b) {
    F3 r;
    r.x = a.y * b.z - a.z * b.y;
    r.y = a.z * b.x - a.x * b.z;
    r.z = a.x * b.y - a.y * b.x;
    return r;
}

// angle = pi - acos(clip(dot(na_hat, nb_hat)))
__device__ __forceinline__ float edge_angle(F3 p0, F3 p1, F3 p2, F3 p3) {
    F3 na = cross3(sub3(p2, p0), sub3(p1, p0));
    F3 nb = cross3(sub3(p3, p1), sub3(p0, p1));
    float la = fmaxf(sqrtf(na.x * na.x + na.y * na.y + na.z * na.z), 1e-12f);
    float lb = fmaxf(sqrtf(nb.x * nb.x + nb.y * nb.y + nb.z * nb.z), 1e-12f);
    // zero normal (degenerate edge): na==0 exactly -> dot=0 -> angle=pi/2, matches ref
    float d = (na.x * nb.x + na.y * nb.y + na.z * nb.z) * (1.0f / la) * (1.0f / lb);
    d = fminf(fmaxf(d, -CLIPV), CLIPV);
    return 3.14159265358979323846f - acosf(d);
}

// ws layout: [0] double accumulator; byte 8: unsigned ticket counter; byte PK_OFF: packed verts
__global__ void mdal_zero_ws_kernel(double* __restrict__ ws) {
    if (threadIdx.x == 0 && blockIdx.x == 0) ws[0] = 0.0;
}

// Interleave vert1/vert2 into 32B records [x1,y1,z1,x2,y2,z2,0,0] in ws.
// Block 0 also initializes the accumulator + ticket counter.
__global__ __launch_bounds__(TPB) void mdal_repack_kernel(
    const float* __restrict__ vert1,
    const float* __restrict__ vert2,
    float* __restrict__ pk,
    double* __restrict__ ws)
{
    if (blockIdx.x == 0 && threadIdx.x == 0) {
        ws[0] = 0.0;
        reinterpret_cast<unsigned*>(ws)[2] = 0u;  // ticket counter at byte 8
    }
    const int bid = blockIdx.x;
    const int b = bid & (NB - 1);
    const int chunk = bid >> 3;
    const int v = chunk * TPB + threadIdx.x;
    if (v >= NV) return;
    const long long src = ((long long)b * NV + v) * 3;
    const long long dst = ((long long)b * NV + v) * 8;
    float x1 = vert1[src], y1 = vert1[src + 1], z1 = vert1[src + 2];
    float x2 = vert2[src], y2 = vert2[src + 1], z2 = vert2[src + 2];
    v4f lo = {x1, y1, z1, x2};
    v4f hi = {y2, z2, 0.0f, 0.0f};
    *reinterpret_cast<v4f*>(pk + dst) = lo;
    *reinterpret_cast<v4f*>(pk + dst + 4) = hi;
}

// Lane-pair cooperative kernel: lanes (2i,2i+1) handle the same edge; each
// loads 16B of the 32B record (same 64B line, same instruction -> TA merges
// to ONE L2 request). Lane h computes mesh-h's dihedral angle; identical
// code path for both lanes (h-selects are cndmask, no divergence).
__global__ __launch_bounds__(TPB, 4) void mdal_main_pk2_kernel(
    const float* __restrict__ pk,
    const int* __restrict__ edge_points,
    double* __restrict__ ws,
    float* __restrict__ out)
{
    const int bid = blockIdx.x;
    const int b = bid & (NB - 1);   // XCD swizzle: XCD k serves only batch k
    const int chunk = bid >> 3;

    const v4i* __restrict__ ep =
        reinterpret_cast<const v4i*>(edge_points) + (long long)b * NE;
    const float* __restrict__ pkb = pk + (long long)b * NV * 8;

    const int h = threadIdx.x & 1;      // which mesh this lane computes
    const int p = threadIdx.x >> 1;     // pair id within block

    double acc = 0.0;

    #pragma unroll
    for (int k = 0; k < EPT; ++k) {
        const int e = chunk * EPB2 + k * PPB + p;
        const bool ok = (e < NE);
        v4i idx;
        if (ok) {
            idx = __builtin_nontemporal_load(&ep[e]);   // both lanes: same line, merged
        } else {
            idx = (v4i){0, 0, 0, 0};
        }

        // 4 half-record gathers; pair covers the full 32B record
        v4f R[4];
        #pragma unroll
        for (int j = 0; j < 4; ++j) {
            const int vid = (j == 0) ? idx.x : (j == 1) ? idx.y
                          : (j == 2) ? idx.z : idx.w;
            R[j] = *reinterpret_cast<const v4f*>(pkb + (long long)vid * 8 + h * 4);
        }

        // redistribute: odd lane needs x2 (= even lane's R.w)
        F3 P[4];
        #pragma unroll
        for (int j = 0; j < 4; ++j) {
            const float xw = __shfl_xor(R[j].w, 1);
            // even (h=0): R=(x1,y1,z1,x2) -> P=(R.x,R.y,R.z)
            // odd  (h=1): R=(y2,z2,0,0), xw=x2 -> P=(xw,R.x,R.y)
            P[j].x = h ? xw   : R[j].x;
            P[j].y = h ? R[j].x : R[j].y;
            P[j].z = h ? R[j].y : R[j].z;
        }

        const float a = edge_angle(P[0], P[1], P[2], P[3]);
        const float d = a - __shfl_xor(a, 1);  // even: a1-a2, odd: a2-a1
        if (ok) acc += (double)d * (double)d;  // both lanes: sum is 2x, halved at end
    }

    // --- wave (64-lane) reduction, then block, then one atomic
    for (int off = 32; off > 0; off >>= 1)
        acc += __shfl_down(acc, off);

    __shared__ double sdata[TPB / 64];
    const int lane = threadIdx.x & 63;
    const int wave = threadIdx.x >> 6;
    if (lane == 0) sdata[wave] = acc;
    __syncthreads();
    if (threadIdx.x == 0) {
        double s = 0.0;
        #pragma unroll
        for (int w = 0; w < TPB / 64; ++w) s += sdata[w];
        atomicAdd(ws, s);
        __threadfence();
        unsigned* counter = reinterpret_cast<unsigned*>(ws) + 2;
        unsigned ticket = atomicAdd(counter, 1u);
        if (ticket == (unsigned)(gridDim.x - 1)) {
            double total = atomicAdd(ws, 0.0);  // atomic read: bypass stale L1
            out[0] = (float)(total / (2.0 * (double)((long long)NB * NE)));
        }
    }
}

// --- fallback path (no workspace repack) ---
__global__ __launch_bounds__(TPB, 4) void mdal_main_kernel(
    const float* __restrict__ vert1,
    const float* __restrict__ vert2,
    const int* __restrict__ edge_points,
    double* __restrict__ ws)
{
    const int bid = blockIdx.x;
    const int b = bid & (NB - 1);
    const int chunk = bid >> 3;
    const int e = chunk * TPB + threadIdx.x;

    const v4i* __restrict__ ep =
        reinterpret_cast<const v4i*>(edge_points) + (long long)b * NE;
    const float* __restrict__ v1 = vert1 + (long long)b * NV * 3;
    const float* __restrict__ v2 = vert2 + (long long)b * NV * 3;

    double acc = 0.0;
    if (e < NE) {
        const v4i idx = ep[e];
        F3 A[4], Bv[4];
        #pragma unroll
        for (int j = 0; j < 4; ++j) {
            const int vid = (j == 0) ? idx.x : (j == 1) ? idx.y
                          : (j == 2) ? idx.z : idx.w;
            const float* pa = v1 + 3LL * vid;
            const float* pb = v2 + 3LL * vid;
            A[j].x = pa[0]; A[j].y = pa[1]; A[j].z = pa[2];
            Bv[j].x = pb[0]; Bv[j].y = pb[1]; Bv[j].z = pb[2];
        }
        float a1 = edge_angle(A[0], A[1], A[2], A[3]);
        float a2 = edge_angle(Bv[0], Bv[1], Bv[2], Bv[3]);
        float d = a1 - a2;
        acc = (double)d * (double)d;
    }

    for (int off = 32; off > 0; off >>= 1)
        acc += __shfl_down(acc, off);

    __shared__ double sdata[TPB / 64];
    const int lane = threadIdx.x & 63;
    const int wave = threadIdx.x >> 6;
    if (lane == 0) sdata[wave] = acc;
    __syncthreads();
    if (threadIdx.x == 0) {
        double s = 0.0;
        #pragma unroll
        for (int w = 0; w < TPB / 64; ++w) s += sdata[w];
        atomicAdd(ws, s);
    }
}

__global__ void mdal_finalize_kernel(const double* __restrict__ ws,
                                     float* __restrict__ out) {
    if (threadIdx.x == 0 && blockIdx.x == 0)
        out[0] = (float)(ws[0] / (double)((long long)NB * NE));
}

extern "C" void kernel_launch(void* const* d_in, const int* in_sizes, int n_in,
                              void* d_out, int out_size, void* d_ws, size_t ws_size,
                              hipStream_t stream) {
    const float* vert1 = (const float*)d_in[0];
    const float* vert2 = (const float*)d_in[1];
    const int* edge_points = (const int*)d_in[2];
    float* out = (float*)d_out;
    double* ws = (double*)d_ws;

    if (ws_size >= PK_OFF + PK_BYTES) {
        float* pk = (float*)((char*)d_ws + PK_OFF);
        mdal_repack_kernel<<<VCHUNKS * NB, TPB, 0, stream>>>(vert1, vert2, pk, ws);
        mdal_main_pk2_kernel<<<CHUNKS2 * NB, TPB, 0, stream>>>(pk, edge_points, ws, out);
    } else {
        mdal_zero_ws_kernel<<<1, 64, 0, stream>>>(ws);
        mdal_main_kernel<<<((NE + TPB - 1) / TPB) * NB, TPB, 0, stream>>>(
            vert1, vert2, edge_points, ws);
        mdal_finalize_kernel<<<1, 64, 0, stream>>>(ws, out);
    }
}

// Round 13
// 460.138 us; speedup vs baseline: 1.0026x; 1.0026x over previous
//
#include <hip/hip_runtime.h>

#define NB 8
#define NV 100000
#define NE 300000
#define CLIPV 0.9999999f  // 1 - 1e-7 rounded to f32

#define TPB 256
#define PPB (TPB / 2)                   // 128 lane-pairs per block
#define EPT 2                           // edges per pair
#define EPB2 (PPB * EPT)                // 256 edges per block
#define CHUNKS2 ((NE + EPB2 - 1) / EPB2)
#define VCHUNKS ((NV + TPB - 1) / TPB)

#define PK_OFF 256                      // byte offset of packed verts in ws
#define PK_BYTES ((size_t)NB * NV * 8 * sizeof(float))

typedef int v4i __attribute__((ext_vector_type(4)));
typedef float v4f __attribute__((ext_vector_type(4)));

struct F3 { float x, y, z; };

__device__ __forceinline__ F3 sub3(F3 a, F3 b) {
    F3 r; r.x = a.x - b.x; r.y = a.y - b.y; r.z = a.z - b.z; return r;
}
__device__ __forceinline__ F3 cross3(F3 a, F3 b) {
    F3 r;
    r.x = a.y * b.z - a.z * b.y;
    r.y = a.z * b.x - a.x * b.z;
    r.z = a.x * b.y - a.y * b.x;
    return r;
}

// angle = pi - acos(clip(dot(na_hat, nb_hat)))
__device__ __forceinline__ float edge_angle(F3 p0, F3 p1, F3 p2, F3 p3) {
    F3 na = cross3(sub3(p2, p0), sub3(p1, p0));
    F3 nb = cross3(sub3(p3, p1), sub3(p0, p1));
    float la = fmaxf(sqrtf(na.x * na.x + na.y * na.y + na.z * na.z), 1e-12f);
    float lb = fmaxf(sqrtf(nb.x * nb.x + nb.y * nb.y + nb.z * nb.z), 1e-12f);
    // zero normal (degenerate edge): na==0 exactly -> dot=0 -> angle=pi/2, matches ref
    float d = (na.x * nb.x + na.y * nb.y + na.z * nb.z) * (1.0f / la) * (1.0f / lb);
    d = fminf(fmaxf(d, -CLIPV), CLIPV);
    return 3.14159265358979323846f - acosf(d);
}

// ws layout: [0] double accumulator; byte 8: unsigned ticket counter; byte PK_OFF: packed verts
__global__ void mdal_zero_ws_kernel(double* __restrict__ ws) {
    if (threadIdx.x == 0 && blockIdx.x == 0) ws[0] = 0.0;
}

// Record: [x1,y1,z1,pad, x2,y2,z2,pad] = 32B, both halves 16B-aligned.
// Block 0 also initializes the accumulator + ticket counter.
__global__ __launch_bounds__(TPB) void mdal_repack_kernel(
    const float* __restrict__ vert1,
    const float* __restrict__ vert2,
    float* __restrict__ pk,
    double* __restrict__ ws)
{
    if (blockIdx.x == 0 && threadIdx.x == 0) {
        ws[0] = 0.0;
        reinterpret_cast<unsigned*>(ws)[2] = 0u;  // ticket counter at byte 8
    }
    const int bid = blockIdx.x;
    const int b = bid & (NB - 1);
    const int chunk = bid >> 3;
    const int v = chunk * TPB + threadIdx.x;
    if (v >= NV) return;
    const long long src = ((long long)b * NV + v) * 3;
    const long long dst = ((long long)b * NV + v) * 8;
    v4f lo = {vert1[src], vert1[src + 1], vert1[src + 2], 0.0f};
    v4f hi = {vert2[src], vert2[src + 1], vert2[src + 2], 0.0f};
    *reinterpret_cast<v4f*>(pk + dst) = lo;
    *reinterpret_cast<v4f*>(pk + dst + 4) = hi;
}

// Lane-pair kernel v2: lanes (2i,2i+1) handle the same edge. Lane h does ONE
// aligned dwordx4 per vertex at record+h*16 -> gets mesh-h's full (x,y,z).
// Pair's two loads hit the same 64B line in the same instruction -> TA merges
// to one L2 request (4 line-requests/edge instead of 8). Only cross-lane op:
// one shfl for the angle difference.
__global__ __launch_bounds__(TPB, 4) void mdal_main_pk3_kernel(
    const float* __restrict__ pk,
    const int* __restrict__ edge_points,
    double* __restrict__ ws,
    float* __restrict__ out)
{
    const int bid = blockIdx.x;
    const int b = bid & (NB - 1);   // XCD swizzle: XCD k serves only batch k
    const int chunk = bid >> 3;

    const v4i* __restrict__ ep =
        reinterpret_cast<const v4i*>(edge_points) + (long long)b * NE;
    const float* __restrict__ pkb = pk + (long long)b * NV * 8 + (threadIdx.x & 1) * 4;

    const int p = threadIdx.x >> 1;     // pair id within block

    double acc = 0.0;

    #pragma unroll
    for (int k = 0; k < EPT; ++k) {
        const int e = chunk * EPB2 + k * PPB + p;
        const bool ok = (e < NE);
        v4i idx;
        if (ok) {
            idx = __builtin_nontemporal_load(&ep[e]);   // both lanes same line -> merged
        } else {
            idx = (v4i){0, 0, 0, 0};
        }

        // one aligned 16B gather per vertex; pair covers both meshes
        F3 P[4];
        #pragma unroll
        for (int j = 0; j < 4; ++j) {
            const int vid = (j == 0) ? idx.x : (j == 1) ? idx.y
                          : (j == 2) ? idx.z : idx.w;
            const v4f R = *reinterpret_cast<const v4f*>(pkb + (long long)vid * 8);
            P[j].x = R.x; P[j].y = R.y; P[j].z = R.z;
        }

        const float a = edge_angle(P[0], P[1], P[2], P[3]);
        const float d = a - __shfl_xor(a, 1);  // even: a1-a2, odd: a2-a1
        if (ok) acc += (double)d * (double)d;  // 2x-counted; halved in finalize
    }

    // --- wave (64-lane) reduction, then block, then one atomic
    for (int off = 32; off > 0; off >>= 1)
        acc += __shfl_down(acc, off);

    __shared__ double sdata[TPB / 64];
    const int lane = threadIdx.x & 63;
    const int wave = threadIdx.x >> 6;
    if (lane == 0) sdata[wave] = acc;
    __syncthreads();
    if (threadIdx.x == 0) {
        double s = 0.0;
        #pragma unroll
        for (int w = 0; w < TPB / 64; ++w) s += sdata[w];
        atomicAdd(ws, s);
        __threadfence();
        unsigned* counter = reinterpret_cast<unsigned*>(ws) + 2;
        unsigned ticket = atomicAdd(counter, 1u);
        if (ticket == (unsigned)(gridDim.x - 1)) {
            double total = atomicAdd(ws, 0.0);  // atomic read: bypass stale L1
            out[0] = (float)(total / (2.0 * (double)((long long)NB * NE)));
        }
    }
}

// --- fallback path (no workspace repack) ---
__global__ __launch_bounds__(TPB, 4) void mdal_main_kernel(
    const float* __restrict__ vert1,
    const float* __restrict__ vert2,
    const int* __restrict__ edge_points,
    double* __restrict__ ws)
{
    const int bid = blockIdx.x;
    const int b = bid & (NB - 1);
    const int chunk = bid >> 3;
    const int e = chunk * TPB + threadIdx.x;

    const v4i* __restrict__ ep =
        reinterpret_cast<const v4i*>(edge_points) + (long long)b * NE;
    const float* __restrict__ v1 = vert1 + (long long)b * NV * 3;
    const float* __restrict__ v2 = vert2 + (long long)b * NV * 3;

    double acc = 0.0;
    if (e < NE) {
        const v4i idx = ep[e];
        F3 A[4], Bv[4];
        #pragma unroll
        for (int j = 0; j < 4; ++j) {
            const int vid = (j == 0) ? idx.x : (j == 1) ? idx.y
                          : (j == 2) ? idx.z : idx.w;
            const float* pa = v1 + 3LL * vid;
            const float* pb = v2 + 3LL * vid;
            A[j].x = pa[0]; A[j].y = pa[1]; A[j].z = pa[2];
            Bv[j].x = pb[0]; Bv[j].y = pb[1]; Bv[j].z = pb[2];
        }
        float a1 = edge_angle(A[0], A[1], A[2], A[3]);
        float a2 = edge_angle(Bv[0], Bv[1], Bv[2], Bv[3]);
        float d = a1 - a2;
        acc = (double)d * (double)d;
    }

    for (int off = 32; off > 0; off >>= 1)
        acc += __shfl_down(acc, off);

    __shared__ double sdata[TPB / 64];
    const int lane = threadIdx.x & 63;
    const int wave = threadIdx.x >> 6;
    if (lane == 0) sdata[wave] = acc;
    __syncthreads();
    if (threadIdx.x == 0) {
        double s = 0.0;
        #pragma unroll
        for (int w = 0; w < TPB / 64; ++w) s += sdata[w];
        atomicAdd(ws, s);
    }
}

__global__ void mdal_finalize_kernel(const double* __restrict__ ws,
                                     float* __restrict__ out) {
    if (threadIdx.x == 0 && blockIdx.x == 0)
        out[0] = (float)(ws[0] / (double)((long long)NB * NE));
}

extern "C" void kernel_launch(void* const* d_in, const int* in_sizes, int n_in,
                              void* d_out, int out_size, void* d_ws, size_t ws_size,
                              hipStream_t stream) {
    const float* vert1 = (const float*)d_in[0];
    const float* vert2 = (const float*)d_in[1];
    const int* edge_points = (const int*)d_in[2];
    float* out = (float*)d_out;
    double* ws = (double*)d_ws;

    if (ws_size >= PK_OFF + PK_BYTES) {
        float* pk = (float*)((char*)d_ws + PK_OFF);
        mdal_repack_kernel<<<VCHUNKS * NB, TPB, 0, stream>>>(vert1, vert2, pk, ws);
        mdal_main_pk3_kernel<<<CHUNKS2 * NB, TPB, 0, stream>>>(pk, edge_points, ws, out);
    } else {
        mdal_zero_ws_kernel<<<1, 64, 0, stream>>>(ws);
        mdal_main_kernel<<<((NE + TPB - 1) / TPB) * NB, TPB, 0, stream>>>(
            vert1, vert2, edge_points, ws);
        mdal_finalize_kernel<<<1, 64, 0, stream>>>(ws, out);
    }
}